// Round 4
// baseline (1469.879 us; speedup 1.0000x reference)
//
#include <hip/hip_runtime.h>
#include <stdint.h>

#define BB 8
#define NN 8192
#define NPOINT 1024
#define NSAMPLE 32

__device__ __forceinline__ unsigned long long u64max(unsigned long long a,
                                                     unsigned long long b) {
    return (a > b) ? a : b;
}

// One DPP max step on a u64 key. Invalid/masked-off lanes contribute 0
// (identity for unsigned max): old=0, bound_ctrl=true.
template <int CTRL, int RMASK>
__device__ __forceinline__ unsigned long long dpp_max_step(unsigned long long key) {
    int lo = (int)(unsigned int)(key & 0xffffffffull);
    int hi = (int)(unsigned int)(key >> 32);
    int tlo = __builtin_amdgcn_update_dpp(0, lo, CTRL, RMASK, 0xF, true);
    int thi = __builtin_amdgcn_update_dpp(0, hi, CTRL, RMASK, 0xF, true);
    unsigned long long t = ((unsigned long long)(unsigned int)thi << 32) |
                           (unsigned long long)(unsigned int)tlo;
    return u64max(key, t);
}

// Full wave64 max-reduce; result valid in lane 63.
__device__ __forceinline__ unsigned long long dpp_wave_max(unsigned long long key) {
    key = dpp_max_step<0x111, 0xF>(key);  // row_shr:1
    key = dpp_max_step<0x112, 0xF>(key);  // row_shr:2
    key = dpp_max_step<0x114, 0xF>(key);  // row_shr:4
    key = dpp_max_step<0x118, 0xF>(key);  // row_shr:8
    key = dpp_max_step<0x142, 0xA>(key);  // row_bcast:15 -> rows 1,3
    key = dpp_max_step<0x143, 0xC>(key);  // row_bcast:31 -> rows 2,3
    return key;
}

// ---------------------------------------------------------------------------
// Kernel 1: farthest point sampling. One block (512 threads, 16 pts/thread)
// per batch. 16 pts/thread keeps live VGPRs ~90 (R3's 32 pts/thread spilled:
// VGPR_Count=132 < needed => accvgpr spill traffic ~550 cyc/iter).
// Bit-exact vs numpy: d2 = ((dx*dx + dy*dy) + dz*dz), fp contract OFF;
// argmax ties -> lowest index (strict > within thread over ascending idx;
// u64 (bits<<32)|~idx across threads). One barrier/iter, double-buffered
// wred; selected coords stored to global directly by t0 (no final gather).
// ---------------------------------------------------------------------------
__global__ __launch_bounds__(512) void fps_kernel(const float* __restrict__ xyz,
                                                  float* __restrict__ new_xyz) {
#pragma clang fp contract(off)
    __shared__ float sx[NN];
    __shared__ float sy[NN];
    __shared__ float sz[NN];
    __shared__ __align__(16) unsigned long long wred[2][8];

    const int b = blockIdx.x;
    const int t = threadIdx.x;
    const int lane = t & 63;
    const int wv = t >> 6;                  // 8 waves
    const float* base = xyz + (size_t)b * NN * 3;

    float2 px[8], py[8], pz[8];             // pair i = points (2i, 2i+1)
    float dist[16];
#pragma unroll
    for (int i = 0; i < 16; ++i) {
        int p = t + (i << 9);               // lane-consecutive: coalesced glb
        float x = base[p * 3 + 0];
        float y = base[p * 3 + 1];
        float z = base[p * 3 + 2];
        sx[p] = x; sy[p] = y; sz[p] = z;
        ((float*)px)[i] = x;
        ((float*)py)[i] = y;
        ((float*)pz)[i] = z;
        dist[i] = 1e10f;                    // f32(10000000000.0) exact
    }
    __syncthreads();

    float lx = sx[0], ly = sy[0], lz = sz[0];   // LDS broadcast of point 0
    float* outb = new_xyz + (size_t)b * NPOINT * 3;
    if (t == 0) { outb[0] = lx; outb[1] = ly; outb[2] = lz; }

    for (int j = 1; j < NPOINT; ++j) {
        float bd = -1.0f;
        int bi = 0;
        const float2 lx2 = make_float2(lx, lx);
        const float2 ly2 = make_float2(ly, ly);
        const float2 lz2 = make_float2(lz, lz);
#pragma unroll
        for (int i = 0; i < 8; ++i) {
            // packed (v_pk-eligible) coordinate math; IEEE rn, no contraction
            float2 dx = make_float2(px[i].x - lx2.x, px[i].y - lx2.y);
            float2 dy = make_float2(py[i].x - ly2.x, py[i].y - ly2.y);
            float2 dz = make_float2(pz[i].x - lz2.x, pz[i].y - lz2.y);
            float2 xx = make_float2(dx.x * dx.x, dx.y * dx.y);
            float2 yy = make_float2(dy.x * dy.x, dy.y * dy.y);
            float2 zz = make_float2(dz.x * dz.x, dz.y * dz.y);
            float2 s  = make_float2(xx.x + yy.x, xx.y + yy.y);
            float2 d2 = make_float2(s.x + zz.x, s.y + zz.y);
            // element 2i first (lower global idx), then 2i+1: strict > keeps
            // the lowest index on ties.
            float da = fminf(dist[2 * i], d2.x);
            dist[2 * i] = da;
            bool ga = da > bd;
            bd = ga ? da : bd;
            bi = ga ? (2 * i) : bi;
            float db = fminf(dist[2 * i + 1], d2.y);
            dist[2 * i + 1] = db;
            bool gb = db > bd;
            bd = gb ? db : bd;
            bi = gb ? (2 * i + 1) : bi;
        }
        int gi = t + (bi << 9);
        unsigned long long key =
            ((unsigned long long)__float_as_uint(bd) << 32) |
            (unsigned long long)(~(unsigned int)gi);      // bigger ~gi == smaller gi
        key = dpp_wave_max(key);
        if (lane == 63) wred[j & 1][wv] = key;
        __syncthreads();
        int cur;
        {
            const unsigned long long* wr = wred[j & 1];
            ulonglong2 p01 = *(const ulonglong2*)&wr[0];  // 4x b128 broadcast
            ulonglong2 p23 = *(const ulonglong2*)&wr[2];
            ulonglong2 p45 = *(const ulonglong2*)&wr[4];
            ulonglong2 p67 = *(const ulonglong2*)&wr[6];
            unsigned long long m =
                u64max(u64max(u64max(p01.x, p01.y), u64max(p23.x, p23.y)),
                       u64max(u64max(p45.x, p45.y), u64max(p67.x, p67.y)));
            cur = (int)(~(unsigned int)(m & 0xffffffffull));
        }
        lx = sx[cur]; ly = sy[cur]; lz = sz[cur];          // LDS broadcast
        if (t == 0) {                                      // fire-and-forget
            outb[j * 3 + 0] = lx;
            outb[j * 3 + 1] = ly;
            outb[j * 3 + 2] = lz;
        }
    }
}

// ---------------------------------------------------------------------------
// Kernel 2: ball query. 4 waves/block, one centroid per wave.
// First NSAMPLE in-radius indices in ascending order, padded with first hit.
// ---------------------------------------------------------------------------
__global__ __launch_bounds__(256) void ballq_kernel(const float* __restrict__ xyz,
                                                    const float* __restrict__ new_xyz,
                                                    int* __restrict__ gidx) {
    __shared__ int s_hits[4][NSAMPLE];
    const int t = threadIdx.x;
    const int lane = t & 63;
    const int wv = t >> 6;
    const int g = blockIdx.x * 4 + wv;        // global centroid id
    const int bi = g >> 10;
    const float R2 = (float)(0.4 * 0.4);      // 0.15999999642f, matches ref

    const float cx = new_xyz[g * 3 + 0];
    const float cy = new_xyz[g * 3 + 1];
    const float cz = new_xyz[g * 3 + 2];
    const float* base = xyz + (size_t)bi * NN * 3;

    int have = 0;
    for (int chunk = 0; chunk < (NN / 64) && have < NSAMPLE; ++chunk) {
        int p = (chunk << 6) + lane;
        float dx = __fsub_rn(cx, base[p * 3 + 0]);
        float dy = __fsub_rn(cy, base[p * 3 + 1]);
        float dz = __fsub_rn(cz, base[p * 3 + 2]);
        float d2 = __fadd_rn(__fadd_rn(__fmul_rn(dx, dx), __fmul_rn(dy, dy)),
                             __fmul_rn(dz, dz));
        bool in = d2 < R2;
        unsigned long long m = __ballot(in);
        int pre = __popcll(m & ((1ull << lane) - 1ull));
        int slot = have + pre;
        if (in && slot < NSAMPLE) s_hits[wv][slot] = p;
        have += (int)__popcll(m);
    }
    __syncthreads();
    if (lane < NSAMPLE) {
        int first = s_hits[wv][0];
        int v = (lane < have) ? s_hits[wv][lane] : first;
        gidx[(size_t)g * NSAMPLE + lane] = v;
    }
}

// ---------------------------------------------------------------------------
// Kernel 3: gather + 3-layer MLP (67->64->64->128) + max over k.
// One block (256 threads) per (b,m) group of 32 points. ~50KB LDS.
// Weights staged transposed (wt[c][o]); wt3 overwrites wt1/wt2 after layer2.
// ---------------------------------------------------------------------------
__global__ __launch_bounds__(256) void mlp_kernel(const float* __restrict__ xyz,
                                                  const float* __restrict__ features,
                                                  const float* __restrict__ w1,
                                                  const float* __restrict__ b1,
                                                  const float* __restrict__ w2,
                                                  const float* __restrict__ b2,
                                                  const float* __restrict__ w3,
                                                  const float* __restrict__ b3,
                                                  const float* __restrict__ new_xyz,
                                                  const int* __restrict__ gidx,
                                                  float* __restrict__ out_feat) {
    __shared__ __align__(16) float s_w[8448];  // wt1[68][64] @0, wt2[64][64] @4352; later wt3[64][128] @0
    __shared__ __align__(16) float s_x[2176];  // x[32][68]; later reused as red[4][128]
    __shared__ __align__(16) float s_h[2048];  // h[32][64]
    __shared__ int s_gi[32];

    const int t = threadIdx.x;
    const int g = blockIdx.x;
    const int bi = g >> 10;
    const int mi = g & 1023;

    // ---- Phase 0: indices + stage wt1, wt2 ----
    if (t < 32) s_gi[t] = gidx[g * 32 + t];
    for (int i = t; i < 4288; i += 256) {          // w1 (64,67) -> wt1[c][o]
        int o = i / 67;
        int c = i - o * 67;
        s_w[c * 64 + o] = w1[i];
    }
    if (t < 64) s_w[67 * 64 + t] = 0.0f;           // zero pad row c=67
    for (int i = t; i < 4096; i += 256) {          // w2 (64,64) -> wt2[c][o]
        int o = i >> 6;
        int c = i & 63;
        s_w[4352 + c * 64 + o] = w2[i];
    }
    __syncthreads();

    // ---- Phase 1: gather x = [xyz_rel(3) | feat(64)], pad c=67 ----
    {
        int cc = t & 63, kg = t >> 6;
#pragma unroll
        for (int r = 0; r < 8; ++r) {
            int k = (kg << 3) + r;
            int row = s_gi[k];
            s_x[k * 68 + 3 + cc] = features[(bi * NN + row) * 64 + cc];
        }
    }
    if (t < 96) {
        int k = t / 3, d = t - k * 3;
        int row = s_gi[k];
        s_x[k * 68 + d] = xyz[(bi * NN + row) * 3 + d] - new_xyz[g * 3 + d];
    }
    if (t < 32) s_x[t * 68 + 67] = 0.0f;
    __syncthreads();

    // ---- Layer 1: 67(+1 pad) -> 64 ----
    const int o = t & 31;
    const int pg = t >> 5;
    const int p0 = pg * 4;
    {
        float acc0[4] = {0.f, 0.f, 0.f, 0.f};
        float acc1[4] = {0.f, 0.f, 0.f, 0.f};
        float bo0 = b1[o], bo1 = b1[o + 32];
        for (int cc = 0; cc < 68; cc += 4) {
            float4 xv[4];
#pragma unroll
            for (int i = 0; i < 4; ++i)
                xv[i] = *(const float4*)&s_x[(p0 + i) * 68 + cc];
#pragma unroll
            for (int jj = 0; jj < 4; ++jj) {
                float wa = s_w[(cc + jj) * 64 + o];
                float wb = s_w[(cc + jj) * 64 + o + 32];
#pragma unroll
                for (int i = 0; i < 4; ++i) {
                    float xc = (jj == 0) ? xv[i].x : (jj == 1) ? xv[i].y
                             : (jj == 2) ? xv[i].z : xv[i].w;
                    acc0[i] += xc * wa;
                    acc1[i] += xc * wb;
                }
            }
        }
#pragma unroll
        for (int i = 0; i < 4; ++i) {
            s_h[(p0 + i) * 64 + o]      = fmaxf(acc0[i] + bo0, 0.0f);
            s_h[(p0 + i) * 64 + o + 32] = fmaxf(acc1[i] + bo1, 0.0f);
        }
    }
    __syncthreads();

    // ---- Layer 2: 64 -> 64 (keep results in regs across the barrier) ----
    {
        float acc0[4] = {0.f, 0.f, 0.f, 0.f};
        float acc1[4] = {0.f, 0.f, 0.f, 0.f};
        float bo0 = b2[o], bo1 = b2[o + 32];
        for (int cc = 0; cc < 64; cc += 4) {
            float4 hv[4];
#pragma unroll
            for (int i = 0; i < 4; ++i)
                hv[i] = *(const float4*)&s_h[(p0 + i) * 64 + cc];
#pragma unroll
            for (int jj = 0; jj < 4; ++jj) {
                float wa = s_w[4352 + (cc + jj) * 64 + o];
                float wb = s_w[4352 + (cc + jj) * 64 + o + 32];
#pragma unroll
                for (int i = 0; i < 4; ++i) {
                    float hc = (jj == 0) ? hv[i].x : (jj == 1) ? hv[i].y
                             : (jj == 2) ? hv[i].z : hv[i].w;
                    acc0[i] += hc * wa;
                    acc1[i] += hc * wb;
                }
            }
        }
        __syncthreads();  // everyone done reading h1 and wt2
#pragma unroll
        for (int i = 0; i < 4; ++i) {
            s_h[(p0 + i) * 64 + o]      = fmaxf(acc0[i] + bo0, 0.0f);
            s_h[(p0 + i) * 64 + o + 32] = fmaxf(acc1[i] + bo1, 0.0f);
        }
    }
    // stage wt3 (overwrites wt1/wt2 region) while h2 is being written
    for (int i = t; i < 8192; i += 256) {          // w3 (128,64) -> wt3[c][o]
        int o3 = i >> 6;
        int c3 = i & 63;
        s_w[c3 * 128 + o3] = w3[i];
    }
    __syncthreads();

    // ---- Layer 3: 64 -> 128, fused max over k ----
    {
        const int oo = t & 63;
        const int qg = t >> 6;
        const int q0 = qg * 8;
        float a0[8] = {0,0,0,0,0,0,0,0};
        float a1[8] = {0,0,0,0,0,0,0,0};
        for (int cc = 0; cc < 64; cc += 4) {
            float wa[4], wb[4];
#pragma unroll
            for (int jj = 0; jj < 4; ++jj) {
                wa[jj] = s_w[(cc + jj) * 128 + oo];
                wb[jj] = s_w[(cc + jj) * 128 + oo + 64];
            }
#pragma unroll
            for (int i = 0; i < 8; ++i) {
                float4 hv = *(const float4*)&s_h[(q0 + i) * 64 + cc];
                a0[i] += hv.x * wa[0] + hv.y * wa[1] + hv.z * wa[2] + hv.w * wa[3];
                a1[i] += hv.x * wb[0] + hv.y * wb[1] + hv.z * wb[2] + hv.w * wb[3];
            }
        }
        float m0 = a0[0], m1 = a1[0];
#pragma unroll
        for (int i = 1; i < 8; ++i) {
            m0 = fmaxf(m0, a0[i]);
            m1 = fmaxf(m1, a1[i]);
        }
        // reduce buffer reuses s_x (dead since layer 1)
        s_x[qg * 128 + oo]      = m0;
        s_x[qg * 128 + oo + 64] = m1;
    }
    __syncthreads();
    if (t < 128) {
        float v = fmaxf(fmaxf(s_x[t], s_x[128 + t]),
                        fmaxf(s_x[256 + t], s_x[384 + t]));
        v = fmaxf(v + b3[t], 0.0f);
        out_feat[(size_t)bi * 128 * 1024 + t * 1024 + mi] = v;
    }
}

extern "C" void kernel_launch(void* const* d_in, const int* in_sizes, int n_in,
                              void* d_out, int out_size, void* d_ws, size_t ws_size,
                              hipStream_t stream) {
    const float* xyz      = (const float*)d_in[0];
    const float* features = (const float*)d_in[1];
    const float* w1       = (const float*)d_in[2];
    const float* b1       = (const float*)d_in[3];
    const float* w2       = (const float*)d_in[4];
    const float* b2       = (const float*)d_in[5];
    const float* w3       = (const float*)d_in[6];
    const float* b3       = (const float*)d_in[7];

    float* out      = (float*)d_out;
    float* new_xyz  = out;                         // B*NPOINT*3 = 24576 floats
    float* out_feat = out + BB * NPOINT * 3;       // B*128*NPOINT
    int*   gidx     = (int*)d_ws;                  // B*NPOINT*NSAMPLE ints = 1MB

    fps_kernel<<<BB, 512, 0, stream>>>(xyz, new_xyz);
    ballq_kernel<<<(BB * NPOINT) / 4, 256, 0, stream>>>(xyz, new_xyz, gidx);
    mlp_kernel<<<BB * NPOINT, 256, 0, stream>>>(xyz, features, w1, b1, w2, b2,
                                                w3, b3, new_xyz, gidx, out_feat);
}

// Round 5
// 1422.065 us; speedup vs baseline: 1.0336x; 1.0336x over previous
//
#include <hip/hip_runtime.h>
#include <stdint.h>

#define BB 8
#define NN 8192
#define NPOINT 1024
#define NSAMPLE 32

__device__ __forceinline__ unsigned long long u64max(unsigned long long a,
                                                     unsigned long long b) {
    return (a > b) ? a : b;
}

// One DPP max step on a u64 key. Invalid/masked-off lanes contribute 0
// (identity for unsigned max): old=0, bound_ctrl=true.
template <int CTRL, int RMASK>
__device__ __forceinline__ unsigned long long dpp_max_step(unsigned long long key) {
    int lo = (int)(unsigned int)(key & 0xffffffffull);
    int hi = (int)(unsigned int)(key >> 32);
    int tlo = __builtin_amdgcn_update_dpp(0, lo, CTRL, RMASK, 0xF, true);
    int thi = __builtin_amdgcn_update_dpp(0, hi, CTRL, RMASK, 0xF, true);
    unsigned long long t = ((unsigned long long)(unsigned int)thi << 32) |
                           (unsigned long long)(unsigned int)tlo;
    return u64max(key, t);
}

// Full wave64 max-reduce; result valid in lane 63.
__device__ __forceinline__ unsigned long long dpp_wave_max(unsigned long long key) {
    key = dpp_max_step<0x111, 0xF>(key);  // row_shr:1
    key = dpp_max_step<0x112, 0xF>(key);  // row_shr:2
    key = dpp_max_step<0x114, 0xF>(key);  // row_shr:4
    key = dpp_max_step<0x118, 0xF>(key);  // row_shr:8
    key = dpp_max_step<0x142, 0xA>(key);  // row_bcast:15 -> rows 1,3
    key = dpp_max_step<0x143, 0xC>(key);  // row_bcast:31 -> rows 2,3
    return key;
}

// ---------------------------------------------------------------------------
// Kernel 1: farthest point sampling. One block (512 threads, 16 pts/thread)
// per batch. SCALAR __f*_rn math (R4's float2 pack doubled instr count:
// VALUBusy 82% of a longer iter). 16 pts/thread => ~88 VGPR, no spills,
// 2 waves/SIMD hide the DPP/barrier tail.
// Bit-exact vs numpy: d2 = ((dx*dx + dy*dy) + dz*dz); argmax ties -> lowest
// index (strict > within thread over ascending idx; u64 (bits<<32)|~idx
// across threads). One barrier/iter, double-buffered wred; selected coords
// stored to global directly by t0 (fire-and-forget).
// ---------------------------------------------------------------------------
__global__ __launch_bounds__(512) void fps_kernel(const float* __restrict__ xyz,
                                                  float* __restrict__ new_xyz) {
    __shared__ float sx[NN];
    __shared__ float sy[NN];
    __shared__ float sz[NN];
    __shared__ __align__(16) unsigned long long wred[2][8];

    const int b = blockIdx.x;
    const int t = threadIdx.x;
    const int lane = t & 63;
    const int wv = t >> 6;                  // 8 waves
    const float* base = xyz + (size_t)b * NN * 3;

    float px[16], py[16], pz[16], dist[16];
#pragma unroll
    for (int i = 0; i < 16; ++i) {
        int p = t + (i << 9);               // lane-consecutive: coalesced glb,
        float x = base[p * 3 + 0];          // conflict-free LDS (bank = t%32)
        float y = base[p * 3 + 1];
        float z = base[p * 3 + 2];
        sx[p] = x; sy[p] = y; sz[p] = z;
        px[i] = x; py[i] = y; pz[i] = z;
        dist[i] = 1e10f;                    // f32(10000000000.0) exact
    }
    __syncthreads();

    float lx = sx[0], ly = sy[0], lz = sz[0];   // LDS broadcast of point 0
    float* outb = new_xyz + (size_t)b * NPOINT * 3;
    if (t == 0) { outb[0] = lx; outb[1] = ly; outb[2] = lz; }

    for (int j = 1; j < NPOINT; ++j) {
        float bd = -1.0f;
        int bi = 0;
#pragma unroll
        for (int i = 0; i < 16; ++i) {
            float dx = __fsub_rn(px[i], lx);
            float dy = __fsub_rn(py[i], ly);
            float dz = __fsub_rn(pz[i], lz);
            float d2 = __fadd_rn(__fadd_rn(__fmul_rn(dx, dx), __fmul_rn(dy, dy)),
                                 __fmul_rn(dz, dz));
            float dd = fminf(dist[i], d2);
            dist[i] = dd;
            bool gt = dd > bd;              // strict: keeps lowest i on ties
            bd = gt ? dd : bd;
            bi = gt ? i : bi;               // i is an inline constant
        }
        int gi = t + (bi << 9);
        unsigned long long key =
            ((unsigned long long)__float_as_uint(bd) << 32) |
            (unsigned long long)(~(unsigned int)gi);      // bigger ~gi == smaller gi
        key = dpp_wave_max(key);
        if (lane == 63) wred[j & 1][wv] = key;
        __syncthreads();
        int cur;
        {
            const unsigned long long* wr = wred[j & 1];
            ulonglong2 p01 = *(const ulonglong2*)&wr[0];  // 4x b128 broadcast
            ulonglong2 p23 = *(const ulonglong2*)&wr[2];
            ulonglong2 p45 = *(const ulonglong2*)&wr[4];
            ulonglong2 p67 = *(const ulonglong2*)&wr[6];
            unsigned long long m =
                u64max(u64max(u64max(p01.x, p01.y), u64max(p23.x, p23.y)),
                       u64max(u64max(p45.x, p45.y), u64max(p67.x, p67.y)));
            cur = (int)(~(unsigned int)(m & 0xffffffffull));
        }
        lx = sx[cur]; ly = sy[cur]; lz = sz[cur];          // LDS broadcast
        if (t == 0) {                                      // fire-and-forget
            outb[j * 3 + 0] = lx;
            outb[j * 3 + 1] = ly;
            outb[j * 3 + 2] = lz;
        }
    }
}

// ---------------------------------------------------------------------------
// Kernel 2: ball query. 4 waves/block, one centroid per wave.
// First NSAMPLE in-radius indices in ascending order, padded with first hit.
// ---------------------------------------------------------------------------
__global__ __launch_bounds__(256) void ballq_kernel(const float* __restrict__ xyz,
                                                    const float* __restrict__ new_xyz,
                                                    int* __restrict__ gidx) {
    __shared__ int s_hits[4][NSAMPLE];
    const int t = threadIdx.x;
    const int lane = t & 63;
    const int wv = t >> 6;
    const int g = blockIdx.x * 4 + wv;        // global centroid id
    const int bi = g >> 10;
    const float R2 = (float)(0.4 * 0.4);      // 0.15999999642f, matches ref

    const float cx = new_xyz[g * 3 + 0];
    const float cy = new_xyz[g * 3 + 1];
    const float cz = new_xyz[g * 3 + 2];
    const float* base = xyz + (size_t)bi * NN * 3;

    int have = 0;
    for (int chunk = 0; chunk < (NN / 64) && have < NSAMPLE; ++chunk) {
        int p = (chunk << 6) + lane;
        float dx = __fsub_rn(cx, base[p * 3 + 0]);
        float dy = __fsub_rn(cy, base[p * 3 + 1]);
        float dz = __fsub_rn(cz, base[p * 3 + 2]);
        float d2 = __fadd_rn(__fadd_rn(__fmul_rn(dx, dx), __fmul_rn(dy, dy)),
                             __fmul_rn(dz, dz));
        bool in = d2 < R2;
        unsigned long long m = __ballot(in);
        int pre = __popcll(m & ((1ull << lane) - 1ull));
        int slot = have + pre;
        if (in && slot < NSAMPLE) s_hits[wv][slot] = p;
        have += (int)__popcll(m);
    }
    __syncthreads();
    if (lane < NSAMPLE) {
        int first = s_hits[wv][0];
        int v = (lane < have) ? s_hits[wv][lane] : first;
        gidx[(size_t)g * NSAMPLE + lane] = v;
    }
}

// ---------------------------------------------------------------------------
// Kernel 3: gather + 3-layer MLP (67->64->64->128) + max over k.
// One block (256 threads) per (b,m) group of 32 points. ~50KB LDS.
// Weights staged transposed (wt[c][o]); wt3 overwrites wt1/wt2 after layer2.
// ---------------------------------------------------------------------------
__global__ __launch_bounds__(256) void mlp_kernel(const float* __restrict__ xyz,
                                                  const float* __restrict__ features,
                                                  const float* __restrict__ w1,
                                                  const float* __restrict__ b1,
                                                  const float* __restrict__ w2,
                                                  const float* __restrict__ b2,
                                                  const float* __restrict__ w3,
                                                  const float* __restrict__ b3,
                                                  const float* __restrict__ new_xyz,
                                                  const int* __restrict__ gidx,
                                                  float* __restrict__ out_feat) {
    __shared__ __align__(16) float s_w[8448];  // wt1[68][64] @0, wt2[64][64] @4352; later wt3[64][128] @0
    __shared__ __align__(16) float s_x[2176];  // x[32][68]; later reused as red[4][128]
    __shared__ __align__(16) float s_h[2048];  // h[32][64]
    __shared__ int s_gi[32];

    const int t = threadIdx.x;
    const int g = blockIdx.x;
    const int bi = g >> 10;
    const int mi = g & 1023;

    // ---- Phase 0: indices + stage wt1, wt2 ----
    if (t < 32) s_gi[t] = gidx[g * 32 + t];
    for (int i = t; i < 4288; i += 256) {          // w1 (64,67) -> wt1[c][o]
        int o = i / 67;
        int c = i - o * 67;
        s_w[c * 64 + o] = w1[i];
    }
    if (t < 64) s_w[67 * 64 + t] = 0.0f;           // zero pad row c=67
    for (int i = t; i < 4096; i += 256) {          // w2 (64,64) -> wt2[c][o]
        int o = i >> 6;
        int c = i & 63;
        s_w[4352 + c * 64 + o] = w2[i];
    }
    __syncthreads();

    // ---- Phase 1: gather x = [xyz_rel(3) | feat(64)], pad c=67 ----
    {
        int cc = t & 63, kg = t >> 6;
#pragma unroll
        for (int r = 0; r < 8; ++r) {
            int k = (kg << 3) + r;
            int row = s_gi[k];
            s_x[k * 68 + 3 + cc] = features[(bi * NN + row) * 64 + cc];
        }
    }
    if (t < 96) {
        int k = t / 3, d = t - k * 3;
        int row = s_gi[k];
        s_x[k * 68 + d] = xyz[(bi * NN + row) * 3 + d] - new_xyz[g * 3 + d];
    }
    if (t < 32) s_x[t * 68 + 67] = 0.0f;
    __syncthreads();

    // ---- Layer 1: 67(+1 pad) -> 64 ----
    const int o = t & 31;
    const int pg = t >> 5;
    const int p0 = pg * 4;
    {
        float acc0[4] = {0.f, 0.f, 0.f, 0.f};
        float acc1[4] = {0.f, 0.f, 0.f, 0.f};
        float bo0 = b1[o], bo1 = b1[o + 32];
        for (int cc = 0; cc < 68; cc += 4) {
            float4 xv[4];
#pragma unroll
            for (int i = 0; i < 4; ++i)
                xv[i] = *(const float4*)&s_x[(p0 + i) * 68 + cc];
#pragma unroll
            for (int jj = 0; jj < 4; ++jj) {
                float wa = s_w[(cc + jj) * 64 + o];
                float wb = s_w[(cc + jj) * 64 + o + 32];
#pragma unroll
                for (int i = 0; i < 4; ++i) {
                    float xc = (jj == 0) ? xv[i].x : (jj == 1) ? xv[i].y
                             : (jj == 2) ? xv[i].z : xv[i].w;
                    acc0[i] += xc * wa;
                    acc1[i] += xc * wb;
                }
            }
        }
#pragma unroll
        for (int i = 0; i < 4; ++i) {
            s_h[(p0 + i) * 64 + o]      = fmaxf(acc0[i] + bo0, 0.0f);
            s_h[(p0 + i) * 64 + o + 32] = fmaxf(acc1[i] + bo1, 0.0f);
        }
    }
    __syncthreads();

    // ---- Layer 2: 64 -> 64 (keep results in regs across the barrier) ----
    {
        float acc0[4] = {0.f, 0.f, 0.f, 0.f};
        float acc1[4] = {0.f, 0.f, 0.f, 0.f};
        float bo0 = b2[o], bo1 = b2[o + 32];
        for (int cc = 0; cc < 64; cc += 4) {
            float4 hv[4];
#pragma unroll
            for (int i = 0; i < 4; ++i)
                hv[i] = *(const float4*)&s_h[(p0 + i) * 64 + cc];
#pragma unroll
            for (int jj = 0; jj < 4; ++jj) {
                float wa = s_w[4352 + (cc + jj) * 64 + o];
                float wb = s_w[4352 + (cc + jj) * 64 + o + 32];
#pragma unroll
                for (int i = 0; i < 4; ++i) {
                    float hc = (jj == 0) ? hv[i].x : (jj == 1) ? hv[i].y
                             : (jj == 2) ? hv[i].z : hv[i].w;
                    acc0[i] += hc * wa;
                    acc1[i] += hc * wb;
                }
            }
        }
        __syncthreads();  // everyone done reading h1 and wt2
#pragma unroll
        for (int i = 0; i < 4; ++i) {
            s_h[(p0 + i) * 64 + o]      = fmaxf(acc0[i] + bo0, 0.0f);
            s_h[(p0 + i) * 64 + o + 32] = fmaxf(acc1[i] + bo1, 0.0f);
        }
    }
    // stage wt3 (overwrites wt1/wt2 region) while h2 is being written
    for (int i = t; i < 8192; i += 256) {          // w3 (128,64) -> wt3[c][o]
        int o3 = i >> 6;
        int c3 = i & 63;
        s_w[c3 * 128 + o3] = w3[i];
    }
    __syncthreads();

    // ---- Layer 3: 64 -> 128, fused max over k ----
    {
        const int oo = t & 63;
        const int qg = t >> 6;
        const int q0 = qg * 8;
        float a0[8] = {0,0,0,0,0,0,0,0};
        float a1[8] = {0,0,0,0,0,0,0,0};
        for (int cc = 0; cc < 64; cc += 4) {
            float wa[4], wb[4];
#pragma unroll
            for (int jj = 0; jj < 4; ++jj) {
                wa[jj] = s_w[(cc + jj) * 128 + oo];
                wb[jj] = s_w[(cc + jj) * 128 + oo + 64];
            }
#pragma unroll
            for (int i = 0; i < 8; ++i) {
                float4 hv = *(const float4*)&s_h[(q0 + i) * 64 + cc];
                a0[i] += hv.x * wa[0] + hv.y * wa[1] + hv.z * wa[2] + hv.w * wa[3];
                a1[i] += hv.x * wb[0] + hv.y * wb[1] + hv.z * wb[2] + hv.w * wb[3];
            }
        }
        float m0 = a0[0], m1 = a1[0];
#pragma unroll
        for (int i = 1; i < 8; ++i) {
            m0 = fmaxf(m0, a0[i]);
            m1 = fmaxf(m1, a1[i]);
        }
        // reduce buffer reuses s_x (dead since layer 1)
        s_x[qg * 128 + oo]      = m0;
        s_x[qg * 128 + oo + 64] = m1;
    }
    __syncthreads();
    if (t < 128) {
        float v = fmaxf(fmaxf(s_x[t], s_x[128 + t]),
                        fmaxf(s_x[256 + t], s_x[384 + t]));
        v = fmaxf(v + b3[t], 0.0f);
        out_feat[(size_t)bi * 128 * 1024 + t * 1024 + mi] = v;
    }
}

extern "C" void kernel_launch(void* const* d_in, const int* in_sizes, int n_in,
                              void* d_out, int out_size, void* d_ws, size_t ws_size,
                              hipStream_t stream) {
    const float* xyz      = (const float*)d_in[0];
    const float* features = (const float*)d_in[1];
    const float* w1       = (const float*)d_in[2];
    const float* b1       = (const float*)d_in[3];
    const float* w2       = (const float*)d_in[4];
    const float* b2       = (const float*)d_in[5];
    const float* w3       = (const float*)d_in[6];
    const float* b3       = (const float*)d_in[7];

    float* out      = (float*)d_out;
    float* new_xyz  = out;                         // B*NPOINT*3 = 24576 floats
    float* out_feat = out + BB * NPOINT * 3;       // B*128*NPOINT
    int*   gidx     = (int*)d_ws;                  // B*NPOINT*NSAMPLE ints = 1MB

    fps_kernel<<<BB, 512, 0, stream>>>(xyz, new_xyz);
    ballq_kernel<<<(BB * NPOINT) / 4, 256, 0, stream>>>(xyz, new_xyz, gidx);
    mlp_kernel<<<BB * NPOINT, 256, 0, stream>>>(xyz, features, w1, b1, w2, b2,
                                                w3, b3, new_xyz, gidx, out_feat);
}

// Round 6
// 1112.725 us; speedup vs baseline: 1.3210x; 1.2780x over previous
//
#include <hip/hip_runtime.h>
#include <stdint.h>

#define BB 8
#define NN 8192
#define NPOINT 1024
#define NSAMPLE 32
#define XS 104   // x row stride in bf16 elems (cols: 0..63 feat, 64..66 xyz, 67..95 zero, 96..103 dead)
#define HS 72    // h / w2 / w3 row stride in bf16 elems (cols 0..63 used)

typedef short short8 __attribute__((ext_vector_type(8)));
typedef float floatx4 __attribute__((ext_vector_type(4)));

__device__ __forceinline__ unsigned short f2bf(float f) {
    unsigned u = __float_as_uint(f);
    unsigned r = u + 0x7FFFu + ((u >> 16) & 1u);   // RNE to bf16
    return (unsigned short)(r >> 16);
}

__device__ __forceinline__ unsigned long long u64max(unsigned long long a,
                                                     unsigned long long b) {
    return (a > b) ? a : b;
}

template <int CTRL, int RMASK>
__device__ __forceinline__ unsigned long long dpp_max_step(unsigned long long key) {
    int lo = (int)(unsigned int)(key & 0xffffffffull);
    int hi = (int)(unsigned int)(key >> 32);
    int tlo = __builtin_amdgcn_update_dpp(0, lo, CTRL, RMASK, 0xF, true);
    int thi = __builtin_amdgcn_update_dpp(0, hi, CTRL, RMASK, 0xF, true);
    unsigned long long t = ((unsigned long long)(unsigned int)thi << 32) |
                           (unsigned long long)(unsigned int)tlo;
    return u64max(key, t);
}

__device__ __forceinline__ unsigned long long dpp_wave_max(unsigned long long key) {
    key = dpp_max_step<0x111, 0xF>(key);  // row_shr:1
    key = dpp_max_step<0x112, 0xF>(key);  // row_shr:2
    key = dpp_max_step<0x114, 0xF>(key);  // row_shr:4
    key = dpp_max_step<0x118, 0xF>(key);  // row_shr:8
    key = dpp_max_step<0x142, 0xA>(key);  // row_bcast:15
    key = dpp_max_step<0x143, 0xC>(key);  // row_bcast:31
    return key;
}

// ---------------------------------------------------------------------------
// Kernel 1: farthest point sampling — unchanged from R5 (943 us known-good).
// ---------------------------------------------------------------------------
__global__ __launch_bounds__(512) void fps_kernel(const float* __restrict__ xyz,
                                                  float* __restrict__ new_xyz) {
    __shared__ float sx[NN];
    __shared__ float sy[NN];
    __shared__ float sz[NN];
    __shared__ __align__(16) unsigned long long wred[2][8];

    const int b = blockIdx.x;
    const int t = threadIdx.x;
    const int lane = t & 63;
    const int wv = t >> 6;
    const float* base = xyz + (size_t)b * NN * 3;

    float px[16], py[16], pz[16], dist[16];
#pragma unroll
    for (int i = 0; i < 16; ++i) {
        int p = t + (i << 9);
        float x = base[p * 3 + 0];
        float y = base[p * 3 + 1];
        float z = base[p * 3 + 2];
        sx[p] = x; sy[p] = y; sz[p] = z;
        px[i] = x; py[i] = y; pz[i] = z;
        dist[i] = 1e10f;
    }
    __syncthreads();

    float lx = sx[0], ly = sy[0], lz = sz[0];
    float* outb = new_xyz + (size_t)b * NPOINT * 3;
    if (t == 0) { outb[0] = lx; outb[1] = ly; outb[2] = lz; }

    for (int j = 1; j < NPOINT; ++j) {
        float bd = -1.0f;
        int bi = 0;
#pragma unroll
        for (int i = 0; i < 16; ++i) {
            float dx = __fsub_rn(px[i], lx);
            float dy = __fsub_rn(py[i], ly);
            float dz = __fsub_rn(pz[i], lz);
            float d2 = __fadd_rn(__fadd_rn(__fmul_rn(dx, dx), __fmul_rn(dy, dy)),
                                 __fmul_rn(dz, dz));
            float dd = fminf(dist[i], d2);
            dist[i] = dd;
            bool gt = dd > bd;
            bd = gt ? dd : bd;
            bi = gt ? i : bi;
        }
        int gi = t + (bi << 9);
        unsigned long long key =
            ((unsigned long long)__float_as_uint(bd) << 32) |
            (unsigned long long)(~(unsigned int)gi);
        key = dpp_wave_max(key);
        if (lane == 63) wred[j & 1][wv] = key;
        __syncthreads();
        int cur;
        {
            const unsigned long long* wr = wred[j & 1];
            ulonglong2 p01 = *(const ulonglong2*)&wr[0];
            ulonglong2 p23 = *(const ulonglong2*)&wr[2];
            ulonglong2 p45 = *(const ulonglong2*)&wr[4];
            ulonglong2 p67 = *(const ulonglong2*)&wr[6];
            unsigned long long m =
                u64max(u64max(u64max(p01.x, p01.y), u64max(p23.x, p23.y)),
                       u64max(u64max(p45.x, p45.y), u64max(p67.x, p67.y)));
            cur = (int)(~(unsigned int)(m & 0xffffffffull));
        }
        lx = sx[cur]; ly = sy[cur]; lz = sz[cur];
        if (t == 0) {
            outb[j * 3 + 0] = lx;
            outb[j * 3 + 1] = ly;
            outb[j * 3 + 2] = lz;
        }
    }
}

// ---------------------------------------------------------------------------
// Kernel 2: ball query — unchanged.
// ---------------------------------------------------------------------------
__global__ __launch_bounds__(256) void ballq_kernel(const float* __restrict__ xyz,
                                                    const float* __restrict__ new_xyz,
                                                    int* __restrict__ gidx) {
    __shared__ int s_hits[4][NSAMPLE];
    const int t = threadIdx.x;
    const int lane = t & 63;
    const int wv = t >> 6;
    const int g = blockIdx.x * 4 + wv;
    const int bi = g >> 10;
    const float R2 = (float)(0.4 * 0.4);

    const float cx = new_xyz[g * 3 + 0];
    const float cy = new_xyz[g * 3 + 1];
    const float cz = new_xyz[g * 3 + 2];
    const float* base = xyz + (size_t)bi * NN * 3;

    int have = 0;
    for (int chunk = 0; chunk < (NN / 64) && have < NSAMPLE; ++chunk) {
        int p = (chunk << 6) + lane;
        float dx = __fsub_rn(cx, base[p * 3 + 0]);
        float dy = __fsub_rn(cy, base[p * 3 + 1]);
        float dz = __fsub_rn(cz, base[p * 3 + 2]);
        float d2 = __fadd_rn(__fadd_rn(__fmul_rn(dx, dx), __fmul_rn(dy, dy)),
                             __fmul_rn(dz, dz));
        bool in = d2 < R2;
        unsigned long long m = __ballot(in);
        int pre = __popcll(m & ((1ull << lane) - 1ull));
        int slot = have + pre;
        if (in && slot < NSAMPLE) s_hits[wv][slot] = p;
        have += (int)__popcll(m);
    }
    __syncthreads();
    if (lane < NSAMPLE) {
        int first = s_hits[wv][0];
        int v = (lane < have) ? s_hits[wv][lane] : first;
        gidx[(size_t)g * NSAMPLE + lane] = v;
    }
}

// ---------------------------------------------------------------------------
// Kernel 3: gather + 3-layer MLP via bf16 MFMA (16x16x32), fused max-pool.
// Block = 256 thr = 4 waves = 4 m-groups (128 pts). Wave w owns group w.
// x[128][XS] bf16 (feat 0..63 | xyz 64..66 | zeros to 95); weights o-major
// (= MFMA B-layout B[n=lane&15][k=quad*8+j]); A[m=lane&15][k=quad*8+j];
// C/D col=lane&15,row=quad*4+reg. w3 staged over w1/w2; h2 over x. 68KB LDS.
// ---------------------------------------------------------------------------
__global__ __launch_bounds__(256) void mlp_mfma_kernel(
    const float* __restrict__ xyz, const float* __restrict__ features,
    const float* __restrict__ w1, const float* __restrict__ b1,
    const float* __restrict__ w2, const float* __restrict__ b2,
    const float* __restrict__ w3, const float* __restrict__ b3,
    const float* __restrict__ new_xyz, const int* __restrict__ gidx,
    float* __restrict__ out_feat) {
    __shared__ __align__(16) unsigned short s_x[128 * XS];    // 26624 B; later h2[128][HS]
    __shared__ __align__(16) unsigned short s_h[128 * HS];    // 18432 B
    __shared__ __align__(16) unsigned short s_w12[11264];     // w1[64][XS]@0, w2[64][HS]@6656; later w3[128][HS]@0
    __shared__ int s_gi[128];

    const int t = threadIdx.x;
    const int lane = t & 63;
    const int w = t >> 6;
    const int col = lane & 15;
    const int quad = lane >> 4;
    const int blk = blockIdx.x;
    const int bi = blk >> 8;              // 256 blocks per batch

    if (t < 128) s_gi[t] = gidx[blk * 128 + t];
    __syncthreads();

    // ---- stage w1, w2 + gather x ----
    {
        int o = t >> 2, part = t & 3;
        const float* w1r = w1 + o * 67;
#pragma unroll
        for (int i = 0; i < 26; ++i) {
            int c = part * 26 + i;
            float v = 0.0f;
            if (c < 64) v = w1r[3 + c];           // permuted: feats first
            else if (c < 67) v = w1r[c - 64];     // then xyz cols
            s_w12[o * XS + c] = f2bf(v);
        }
        const float* w2r = w2 + o * 64 + part * 16;
#pragma unroll
        for (int i = 0; i < 8; ++i) {
            unsigned pk = (unsigned)f2bf(w2r[2 * i]) |
                          ((unsigned)f2bf(w2r[2 * i + 1]) << 16);
            *(unsigned*)&s_w12[6656 + o * HS + part * 16 + 2 * i] = pk;
        }
    }
    {
        int k = t >> 1, half = t & 1;
        int row = s_gi[k];
        const float4* frow =
            (const float4*)(features + ((size_t)bi * NN + row) * 64) + half * 8;
        unsigned short* xr = &s_x[k * XS + half * 32];
#pragma unroll
        for (int i = 0; i < 8; ++i) {
            float4 v = frow[i];
            unsigned lo = (unsigned)f2bf(v.x) | ((unsigned)f2bf(v.y) << 16);
            unsigned hi = (unsigned)f2bf(v.z) | ((unsigned)f2bf(v.w) << 16);
            *(uint2*)(xr + i * 4) = make_uint2(lo, hi);
        }
    }
    if (t < 128) {
        int k = t;
        int row = s_gi[k];
        int gg = (blk << 2) + (k >> 5);
        const float* pr = xyz + ((size_t)bi * NN + row) * 3;
        const float* cr = new_xyz + (size_t)gg * 3;
        s_x[k * XS + 64] = f2bf(pr[0] - cr[0]);
        s_x[k * XS + 65] = f2bf(pr[1] - cr[1]);
        s_x[k * XS + 66] = f2bf(pr[2] - cr[2]);
        s_x[k * XS + 67] = 0;
        unsigned* z = (unsigned*)&s_x[k * XS + 68];   // byte 136 within row: 4-aligned
#pragma unroll
        for (int i = 0; i < 14; ++i) z[i] = 0;        // cols 68..95
    }
    __syncthreads();

    const int mbase = w * 32;

    // ---- Layer 1: [128 x 96] x [96 -> 64] ----
    floatx4 acc[2][4] = {};
    for (int kk = 0; kk < 3; ++kk) {
        short8 a0 = *(const short8*)&s_x[(mbase + col) * XS + kk * 32 + quad * 8];
        short8 a1 = *(const short8*)&s_x[(mbase + 16 + col) * XS + kk * 32 + quad * 8];
#pragma unroll
        for (int nt = 0; nt < 4; ++nt) {
            short8 b = *(const short8*)&s_w12[(nt * 16 + col) * XS + kk * 32 + quad * 8];
            acc[0][nt] = __builtin_amdgcn_mfma_f32_16x16x32_bf16(a0, b, acc[0][nt], 0, 0, 0);
            acc[1][nt] = __builtin_amdgcn_mfma_f32_16x16x32_bf16(a1, b, acc[1][nt], 0, 0, 0);
        }
    }
#pragma unroll
    for (int nt = 0; nt < 4; ++nt) {
        float bb = b1[nt * 16 + col];
#pragma unroll
        for (int mt = 0; mt < 2; ++mt)
#pragma unroll
            for (int r = 0; r < 4; ++r) {
                float v = fmaxf(acc[mt][nt][r] + bb, 0.0f);
                s_h[(mbase + mt * 16 + quad * 4 + r) * HS + nt * 16 + col] = f2bf(v);
            }
    }
    __syncthreads();

    // ---- Layer 2: [128 x 64] x [64 -> 64], h2 -> s_x region ----
    floatx4 acc2[2][4] = {};
    for (int kk = 0; kk < 2; ++kk) {
        short8 a0 = *(const short8*)&s_h[(mbase + col) * HS + kk * 32 + quad * 8];
        short8 a1 = *(const short8*)&s_h[(mbase + 16 + col) * HS + kk * 32 + quad * 8];
#pragma unroll
        for (int nt = 0; nt < 4; ++nt) {
            short8 b = *(const short8*)&s_w12[6656 + (nt * 16 + col) * HS + kk * 32 + quad * 8];
            acc2[0][nt] = __builtin_amdgcn_mfma_f32_16x16x32_bf16(a0, b, acc2[0][nt], 0, 0, 0);
            acc2[1][nt] = __builtin_amdgcn_mfma_f32_16x16x32_bf16(a1, b, acc2[1][nt], 0, 0, 0);
        }
    }
    unsigned short* s_h2 = s_x;  // x dead after L1
#pragma unroll
    for (int nt = 0; nt < 4; ++nt) {
        float bb = b2[nt * 16 + col];
#pragma unroll
        for (int mt = 0; mt < 2; ++mt)
#pragma unroll
            for (int r = 0; r < 4; ++r) {
                float v = fmaxf(acc2[mt][nt][r] + bb, 0.0f);
                s_h2[(mbase + mt * 16 + quad * 4 + r) * HS + nt * 16 + col] = f2bf(v);
            }
    }
    __syncthreads();   // h2 complete; all w2 reads done

    // ---- stage w3 [128][HS] over w1/w2 ----
    {
        int o = t >> 1, half = t & 1;
        const float* w3r = w3 + o * 64 + half * 32;
#pragma unroll
        for (int i = 0; i < 16; ++i) {
            unsigned pk = (unsigned)f2bf(w3r[2 * i]) |
                          ((unsigned)f2bf(w3r[2 * i + 1]) << 16);
            *(unsigned*)&s_w12[o * HS + half * 32 + 2 * i] = pk;
        }
    }
    __syncthreads();

    // ---- Layer 3: [128 x 64] x [64 -> 128], fused k-maxpool + bias + relu ----
    floatx4 c3[2][8] = {};
    for (int kk = 0; kk < 2; ++kk) {
        short8 a0 = *(const short8*)&s_h2[(mbase + col) * HS + kk * 32 + quad * 8];
        short8 a1 = *(const short8*)&s_h2[(mbase + 16 + col) * HS + kk * 32 + quad * 8];
#pragma unroll
        for (int nt = 0; nt < 8; ++nt) {
            short8 b = *(const short8*)&s_w12[(nt * 16 + col) * HS + kk * 32 + quad * 8];
            c3[0][nt] = __builtin_amdgcn_mfma_f32_16x16x32_bf16(a0, b, c3[0][nt], 0, 0, 0);
            c3[1][nt] = __builtin_amdgcn_mfma_f32_16x16x32_bf16(a1, b, c3[1][nt], 0, 0, 0);
        }
    }
    {
        int gg = (blk << 2) + w;
        float* ob = out_feat + (size_t)bi * (128 * 1024) + (gg & 1023);
#pragma unroll
        for (int nt = 0; nt < 8; ++nt) {
            float m = fmaxf(fmaxf(fmaxf(c3[0][nt][0], c3[0][nt][1]),
                                  fmaxf(c3[0][nt][2], c3[0][nt][3])),
                            fmaxf(fmaxf(c3[1][nt][0], c3[1][nt][1]),
                                  fmaxf(c3[1][nt][2], c3[1][nt][3])));
            m = fmaxf(m, __shfl_xor(m, 16));
            m = fmaxf(m, __shfl_xor(m, 32));
            if (lane < 16) {
                float v = fmaxf(m + b3[nt * 16 + lane], 0.0f);
                ob[(size_t)(nt * 16 + lane) * 1024] = v;
            }
        }
    }
}

extern "C" void kernel_launch(void* const* d_in, const int* in_sizes, int n_in,
                              void* d_out, int out_size, void* d_ws, size_t ws_size,
                              hipStream_t stream) {
    const float* xyz      = (const float*)d_in[0];
    const float* features = (const float*)d_in[1];
    const float* w1       = (const float*)d_in[2];
    const float* b1       = (const float*)d_in[3];
    const float* w2       = (const float*)d_in[4];
    const float* b2       = (const float*)d_in[5];
    const float* w3       = (const float*)d_in[6];
    const float* b3       = (const float*)d_in[7];

    float* out      = (float*)d_out;
    float* new_xyz  = out;                         // B*NPOINT*3
    float* out_feat = out + BB * NPOINT * 3;       // B*128*NPOINT
    int*   gidx     = (int*)d_ws;                  // B*NPOINT*NSAMPLE ints

    fps_kernel<<<BB, 512, 0, stream>>>(xyz, new_xyz);
    ballq_kernel<<<(BB * NPOINT) / 4, 256, 0, stream>>>(xyz, new_xyz, gidx);
    mlp_mfma_kernel<<<(BB * NPOINT) / 4, 256, 0, stream>>>(xyz, features, w1, b1,
                                                           w2, b2, w3, b3,
                                                           new_xyz, gidx, out_feat);
}